// Round 7
// baseline (243237.134 us; speedup 1.0000x reference)
//
#include <hip/hip_runtime.h>
#include <hip/hip_fp16.h>
#include <math.h>

// ---------------------------------------------------------------------------
// Seq2Seq (bi-LSTM encoder x2 + fixed-state decoder), B=64 T=1024 H=256.
// STORAGE IS FP32 (proven: rounds 3/4 passed reading fp32; rounds 2/5/6
// NaN'd reading bf16 — the test's "bf16" label is its threshold mode only).
// BATCH-PARALLEL: one WG per (batch,dir) stream; h/c in LDS/registers; fp32
// weights stream from per-XCD L2 (read-only). 2 global barriers total
// (E0->E1, E1->DEC). Decoder: per-batch WGs, NaN-free bitwise early exit.
// GEMV: 2-way k-split, 4/8 rows/thread, kin broadcast-read from LDS.
// fp32 compute; y0 staged fp16 (r3/r4: absmax=0). LDS ~106KB -> 1 WG/CU.
// ---------------------------------------------------------------------------

#define NWG 256
#define THR 512

// ws layout (4-byte words); words [0..1024) = barrier counters
#define OF_EC0 1024                  // enc l0 final c fp32 [dir*64+b][256]
#define OF_EC1 33792                 // enc l1 final c fp32
#define OF_EH1 66560                 // enc l1 final h fp16 [dir*64+b][256]
#define OF_Y0  82944                 // y0 fp16 [t][b][512]
#define WS_REQ_BYTES ((size_t)(OF_Y0 + 16777216) * 4)   // ~67.4 MB (>=69.2MB proven available)

struct SeqParams {
  const float *x, *eWih0, *eWhh0, *eB0, *eWih1, *eWhh1, *eB1;
  const float *dWih0, *dWhh0, *dB0, *dWih1, *dWhh1, *dB1, *fcW, *fcb;
  float* out;
  float* ws;
  unsigned* ctrs;
};

__device__ __forceinline__ float hf2f(unsigned short u) {
  __half_raw r; r.x = u; return __half2float(__half(r));
}
__device__ __forceinline__ unsigned short f2h_u(float f) {
  __half h = __float2half(f);
  return *reinterpret_cast<unsigned short*>(&h);
}
__device__ __forceinline__ float sigm(float v) { return 1.0f / (1.0f + expf(-v)); }

#define FMA4(acc, v, ka) do { \
  acc += (v).x * (ka).x; acc += (v).y * (ka).y; \
  acc += (v).z * (ka).z; acc += (v).w * (ka).w; } while (0)

// ---- global barrier (round-4 proven): release add, relaxed spin, acquire ----
__device__ __forceinline__ void gbar(unsigned* ctrs, unsigned gen) {
  __syncthreads();
  if (threadIdx.x == 0) {
    __hip_atomic_fetch_add(&ctrs[(blockIdx.x & 31) * 32], 1u,
                           __ATOMIC_RELEASE, __HIP_MEMORY_SCOPE_AGENT);
  }
  if (threadIdx.x < 32) {
    while (__hip_atomic_load(&ctrs[threadIdx.x * 32], __ATOMIC_RELAXED,
                             __HIP_MEMORY_SCOPE_AGENT) < gen * 8u) {
      __builtin_amdgcn_s_sleep(1);
    }
    (void)__hip_atomic_load(&ctrs[threadIdx.x * 32], __ATOMIC_ACQUIRE,
                            __HIP_MEMORY_SCOPE_AGENT);
  }
  __syncthreads();
}

// 1024-row fp32 GEMV, K=256 from kin[0..256), 2-way k-split -> part[0/1][1024]
__device__ __forceinline__ void gemv1024_k256(const float4* W4, const float* kin,
                                              float* part, int t) {
  const int khalf = t >> 8, rg = t & 255;
  const float4* k4 = (const float4*)kin + khalf * 32;
  float a0 = 0.f, a1 = 0.f, a2 = 0.f, a3 = 0.f;
#pragma unroll 4
  for (int ch = 0; ch < 32; ++ch) {
    float4 ka = k4[ch];
    const float4* Wr = W4 + (4 * rg) * 64 + khalf * 32 + ch;
    float4 v0 = Wr[0];
    float4 v1 = Wr[64];
    float4 v2 = Wr[128];
    float4 v3 = Wr[192];
    FMA4(a0, v0, ka); FMA4(a1, v1, ka);
    FMA4(a2, v2, ka); FMA4(a3, v3, ka);
  }
  part[khalf * 1024 + 4 * rg + 0] = a0;
  part[khalf * 1024 + 4 * rg + 1] = a1;
  part[khalf * 1024 + 4 * rg + 2] = a2;
  part[khalf * 1024 + 4 * rg + 3] = a3;
}

// E1: 1024-row fp32 GEMV over K=768: kin[0..512)=y0 via Wih (512 cols, row=128 f4),
// kin[512..768)=h via Whh (256 cols, row=64 f4); balanced 2-way k-split (384|384).
__device__ __forceinline__ void gemv1024_e1(const float4* Wih, const float4* Whh,
                                            const float* kin, float* part, int t) {
  const int khalf = t >> 8, rg = t & 255;
  float a0 = 0.f, a1 = 0.f, a2 = 0.f, a3 = 0.f;
  if (khalf == 0) {
    const float4* k4 = (const float4*)kin;
#pragma unroll 4
    for (int ch = 0; ch < 96; ++ch) {               // Wih cols 0..384
      float4 ka = k4[ch];
      const float4* Wr = Wih + (4 * rg) * 128 + ch;
      float4 v0 = Wr[0];
      float4 v1 = Wr[128];
      float4 v2 = Wr[256];
      float4 v3 = Wr[384];
      FMA4(a0, v0, ka); FMA4(a1, v1, ka);
      FMA4(a2, v2, ka); FMA4(a3, v3, ka);
    }
  } else {
    const float4* k4 = (const float4*)(kin + 384);
#pragma unroll 4
    for (int ch = 0; ch < 32; ++ch) {               // Wih cols 384..512
      float4 ka = k4[ch];
      const float4* Wr = Wih + (4 * rg) * 128 + 96 + ch;
      float4 v0 = Wr[0];
      float4 v1 = Wr[128];
      float4 v2 = Wr[256];
      float4 v3 = Wr[384];
      FMA4(a0, v0, ka); FMA4(a1, v1, ka);
      FMA4(a2, v2, ka); FMA4(a3, v3, ka);
    }
    const float4* k4b = (const float4*)(kin + 512);
#pragma unroll 4
    for (int ch = 0; ch < 64; ++ch) {               // Whh cols 0..256
      float4 ka = k4b[ch];
      const float4* Wr = Whh + (4 * rg) * 64 + ch;
      float4 v0 = Wr[0];
      float4 v1 = Wr[64];
      float4 v2 = Wr[128];
      float4 v3 = Wr[192];
      FMA4(a0, v0, ka); FMA4(a1, v1, ka);
      FMA4(a2, v2, ka); FMA4(a3, v3, ka);
    }
  }
  part[khalf * 1024 + 4 * rg + 0] = a0;
  part[khalf * 1024 + 4 * rg + 1] = a1;
  part[khalf * 1024 + 4 * rg + 2] = a2;
  part[khalf * 1024 + 4 * rg + 3] = a3;
}

// decoder l1: 2048 rows (2 dirs x 1024, row=128 f4) over K=512 (z); 2-way k-split
__device__ __forceinline__ void gemv2048_dec(const float4* Wd, const float* kin,
                                             float* part, int t) {
  const int khalf = t >> 8, rg = t & 255;
  float a[8];
#pragma unroll
  for (int i = 0; i < 8; ++i) a[i] = 0.f;
  const float4* k4 = (const float4*)(kin + khalf * 256);
#pragma unroll 2
  for (int ch = 0; ch < 64; ++ch) {
    float4 ka = k4[ch];
#pragma unroll
    for (int ri = 0; ri < 8; ++ri) {
      int r2 = 8 * rg + ri;
      float4 v = Wd[(r2 >> 10) * 131072 + (r2 & 1023) * 128 + khalf * 64 + ch];
      FMA4(a[ri], v, ka);
    }
  }
#pragma unroll
  for (int ri = 0; ri < 8; ++ri) part[khalf * 2048 + 8 * rg + ri] = a[ri];
}

__global__ void __launch_bounds__(THR, 1) seq2seq_kernel(SeqParams p) {
  __shared__ float kin[1024];      // k-input vector (h / y0+h / z)
  __shared__ float part[20480];    // [0..4096) used; oversized -> 1 WG/CU
  __shared__ float Rl[4096];       // decoder recurrent consts
  __shared__ float xl[1024];       // x[b][:] preload (E0)
  __shared__ float ph[512];
  __shared__ float red[64];
  __shared__ float ysh[4];         // [0]=y_cur, [1]=y_prev (period-2 fill)
  __shared__ int   exsh;

  const int w = blockIdx.x;
  const int t = threadIdx.x;
  float* ws = p.ws;
  unsigned short* y0u = (unsigned short*)(ws + OF_Y0);
  unsigned short* eh1p = (unsigned short*)(ws + OF_EH1);
  unsigned* ctrs = p.ctrs;

  // -------- defensive LDS init --------
  for (int i = t; i < 4096; i += THR) { part[i] = 0.f; Rl[i] = 0.f; }
  for (int i = t; i < 1024; i += THR) { kin[i] = 0.f; xl[i] = 0.f; }
  if (t < 64) red[t] = 0.f;
  ph[t] = 0.f;
  if (t < 4) ysh[t] = 0.f;
  if (t == 0) exsh = 0;
  __syncthreads();

  // ============================ E0 (batch-parallel) ========================
  if (w < 128) {
    const int dir = w >> 6, b = w & 63;
    const float4* W4 = (const float4*)(p.eWhh0 + (size_t)dir * 262144);
    for (int i = t; i < 1024; i += THR) xl[i] = p.x[b * 1024 + i];
    float creg = 0.f, bias[4], w0[4];
    if (t < 256) {
#pragma unroll
      for (int g = 0; g < 4; ++g) {
        bias[g] = p.eB0[dir * 1024 + g * 256 + t];
        w0[g]   = p.eWih0[dir * 1024 + g * 256 + t];
      }
    }
    __syncthreads();
    for (int st = 0; st < 1024; ++st) {
      const int tt = dir ? (1023 - st) : st;
      gemv1024_k256(W4, kin, part, t);
      __syncthreads();
      if (t < 256) {
        float xv = xl[tt];
        float gi = part[t]       + part[1024 + t] + bias[0] + xv * w0[0];
        float gf = part[256 + t] + part[1280 + t] + bias[1] + xv * w0[1];
        float gg = part[512 + t] + part[1536 + t] + bias[2] + xv * w0[2];
        float go = part[768 + t] + part[1792 + t] + bias[3] + xv * w0[3];
        float cn = sigm(gf) * creg + sigm(gi) * tanhf(gg);
        float hn = sigm(go) * tanhf(cn);
        creg = cn;
        kin[t] = hn;
        y0u[((size_t)tt * 64 + b) * 512 + dir * 256 + t] = f2h_u(hn);
      }
      __syncthreads();
    }
    if (t < 256) ws[OF_EC0 + (size_t)(dir * 64 + b) * 256 + t] = creg;
  }
  gbar(ctrs, 1);

  // ============================ E1 (batch-parallel) ========================
  if (w < 128) {
    const int dir = w >> 6, b = w & 63;
    const float4* Wih = (const float4*)(p.eWih1 + (size_t)dir * 524288);
    const float4* Whh = (const float4*)(p.eWhh1 + (size_t)dir * 262144);
    float creg = 0.f, hlast = 0.f, bias[4];
    if (t < 256) {
#pragma unroll
      for (int g = 0; g < 4; ++g)
        bias[g] = p.eB1[dir * 1024 + g * 256 + t];
      kin[512 + t] = 0.f;                // h part of kin
    }
    __syncthreads();
    for (int st = 0; st < 1024; ++st) {
      const int tt = dir ? (1023 - st) : st;
      kin[t] = hf2f(y0u[((size_t)tt * 64 + b) * 512 + t]);   // stage y0 (512 thr)
      __syncthreads();
      gemv1024_e1(Wih, Whh, kin, part, t);
      __syncthreads();
      if (t < 256) {
        float gi = part[t]       + part[1024 + t] + bias[0];
        float gf = part[256 + t] + part[1280 + t] + bias[1];
        float gg = part[512 + t] + part[1536 + t] + bias[2];
        float go = part[768 + t] + part[1792 + t] + bias[3];
        float cn = sigm(gf) * creg + sigm(gi) * tanhf(gg);
        float hn = sigm(go) * tanhf(cn);
        creg = cn; hlast = hn;
        kin[512 + t] = hn;
      }
      __syncthreads();
    }
    if (t < 256) {
      ws[OF_EC1 + (size_t)(dir * 64 + b) * 256 + t] = creg;
      eh1p[(size_t)(dir * 64 + b) * 256 + t] = f2h_u(hlast);
    }
  }
  gbar(ctrs, 2);

  if (w >= 64) return;

  // ====================== decoder (per-batch, no barriers) =================
  {
    const int b = w;
    // ---- R consts: R[m] = Whh_m . eh_m + b_m, m = {l0f, l0b, l1f, l1b} ----
    for (int m = 0; m < 4; ++m) {
      const unsigned short* src =
          (m == 0) ? (y0u + ((size_t)1023 * 64 + b) * 512)        // hf0 final
        : (m == 1) ? (y0u + ((size_t)b) * 512 + 256)              // hb0 final
                   : (eh1p + (size_t)((m - 2) * 64 + b) * 256);   // h1 finals
      const float4* W4 = (m < 2)
          ? (const float4*)(p.dWhh0 + (size_t)(m & 1) * 262144)
          : (const float4*)(p.dWhh1 + (size_t)(m & 1) * 262144);
      const float* bb = (m < 2) ? (p.dB0 + (m & 1) * 1024)
                                : (p.dB1 + (m & 1) * 1024);
      if (t < 256) kin[t] = hf2f(src[t]);
      __syncthreads();
      gemv1024_k256(W4, kin, part, t);
      __syncthreads();
      {
        int r = t;
        Rl[m * 1024 + r] = part[r] + part[1024 + r] + bb[r];
        r = 512 + t;
        Rl[m * 1024 + r] = part[r] + part[1024 + r] + bb[r];
      }
      __syncthreads();
    }

    // ---- per-thread preloads: thread t = (dir dc, col c) cell ----
    const int dc = t >> 8, c = t & 255;
    float w0d[4];
#pragma unroll
    for (int g = 0; g < 4; ++g)
      w0d[g] = p.dWih0[dc * 1024 + g * 256 + c];
    const float cold0 = ws[OF_EC0 + (size_t)(dc * 64 + b) * 256 + c];
    const float cold1 = ws[OF_EC1 + (size_t)(dc * 64 + b) * 256 + c];
    const float fw = p.fcW[dc * 256 + c];
    const float fcb = p.fcb[0];
    const float4* Wd = (const float4*)p.dWih1;
    float yp1 = 0.f, yp2 = 0.f;          // t0-private history (st-guarded)

    for (int st = 0; st < 1024; ++st) {
      // z: decoder l0 cells from scalar y (state re-init from encoder)
      {
        float yv = ysh[0];
        float gi = yv * w0d[0] + Rl[dc * 1024 + c];
        float gf = yv * w0d[1] + Rl[dc * 1024 + 256 + c];
        float gg = yv * w0d[2] + Rl[dc * 1024 + 512 + c];
        float go = yv * w0d[3] + Rl[dc * 1024 + 768 + c];
        float cn = sigm(gf) * cold0 + sigm(gi) * tanhf(gg);
        kin[t] = sigm(go) * tanhf(cn);      // z[dc*256+c]
      }
      __syncthreads();
      gemv2048_dec(Wd, kin, part, t);
      __syncthreads();
      {
        float gi = part[dc * 1024 + c]       + part[2048 + dc * 1024 + c]       + Rl[(2 + dc) * 1024 + c];
        float gf = part[dc * 1024 + 256 + c] + part[2048 + dc * 1024 + 256 + c] + Rl[(2 + dc) * 1024 + 256 + c];
        float gg = part[dc * 1024 + 512 + c] + part[2048 + dc * 1024 + 512 + c] + Rl[(2 + dc) * 1024 + 512 + c];
        float go = part[dc * 1024 + 768 + c] + part[2048 + dc * 1024 + 768 + c] + Rl[(2 + dc) * 1024 + 768 + c];
        float cn = sigm(gf) * cold1 + sigm(gi) * tanhf(gg);
        float h1 = sigm(go) * tanhf(cn);
        ph[t] = h1 * fw;
      }
      __syncthreads();
      if (t < 64) {
        float s = 0.f;
#pragma unroll
        for (int j = 0; j < 8; ++j) s += ph[t * 8 + j];
        red[t] = s;
      }
      __syncthreads();
      if (t == 0) {
        float y = fcb;
        for (int j = 0; j < 64; ++j) y += red[j];
        unsigned uy = __float_as_uint(y);
        if ((uy & 0x7F800000u) == 0x7F800000u) y = 4096.0f;  // diag: non-finite
        p.out[(size_t)b * 1024 + st] = y;
        int ex = 0;
        if (st >= 1 && __float_as_uint(y) == __float_as_uint(yp1)) ex = 1;
        else if (st >= 2 && __float_as_uint(y) == __float_as_uint(yp2)) ex = 2;
        ysh[1] = yp1;                    // y_{st-1}: odd-offset value if ex==2
        yp2 = yp1; yp1 = y;
        ysh[0] = y;
        exsh = ex;
      }
      __syncthreads();
      {
        int ex = exsh;
        if (ex == 1) {                   // exact fixed point: fill & exit
          float y = ysh[0];
          for (int i = st + 1 + t; i < 1024; i += THR)
            p.out[(size_t)b * 1024 + i] = y;
          break;
        }
        if (ex == 2) {                   // exact period-2 cycle
          float y = ysh[0], alt = ysh[1];
          for (int i = st + 1 + t; i < 1024; i += THR)
            p.out[(size_t)b * 1024 + i] = ((i - st) & 1) ? alt : y;
          break;
        }
      }
      __syncthreads();
    }
  }
}

// diagnostic: if ws too small, encode ws_size (MB) into the output signature
__global__ void fill_sig(float* out, int n, float val) {
  int i = blockIdx.x * 256 + threadIdx.x;
  if (i < n) out[i] = val;
}

extern "C" void kernel_launch(void* const* d_in, const int* in_sizes, int n_in,
                              void* d_out, int out_size, void* d_ws, size_t ws_size,
                              hipStream_t stream) {
  (void)in_sizes; (void)n_in;
  if (ws_size < WS_REQ_BYTES) {
    float sig = 2048.0f + (float)(ws_size >> 20);
    fill_sig<<<(out_size + 255) / 256, 256, 0, stream>>>(
        (float*)d_out, out_size, sig);
    return;
  }
  hipMemsetAsync(d_ws, 0, 4096, stream);   // zero barrier counters

  SeqParams p;
  p.x     = (const float*)d_in[0];
  p.eWih0 = (const float*)d_in[1];
  p.eWhh0 = (const float*)d_in[2];
  p.eB0   = (const float*)d_in[3];
  p.eWih1 = (const float*)d_in[4];
  p.eWhh1 = (const float*)d_in[5];
  p.eB1   = (const float*)d_in[6];
  p.dWih0 = (const float*)d_in[7];
  p.dWhh0 = (const float*)d_in[8];
  p.dB0   = (const float*)d_in[9];
  p.dWih1 = (const float*)d_in[10];
  p.dWhh1 = (const float*)d_in[11];
  p.dB1   = (const float*)d_in[12];
  p.fcW   = (const float*)d_in[13];
  p.fcb   = (const float*)d_in[14];
  p.out   = (float*)d_out;
  p.ws    = (float*)d_ws;
  p.ctrs  = (unsigned*)d_ws;

  seq2seq_kernel<<<dim3(NWG), dim3(THR), 0, stream>>>(p);
}

// Round 8
// 75822.705 us; speedup vs baseline: 3.2080x; 3.2080x over previous
//
#include <hip/hip_runtime.h>
#include <hip/hip_fp16.h>
#include <math.h>

// ---------------------------------------------------------------------------
// Seq2Seq (bi-LSTM encoder x2 + fixed-state decoder), B=64 T=1024 H=256, fp32.
// Output-stationary encoder (round-4 proven dot/reduce): 256 WGs x 512 thr,
// each WG owns 8 gate rows (2 h-cols) of one direction; weights LDS-resident.
// h exchanged through LLC as fp16 (E0's h IS y0). Dir-split barrier groups
// (128 WGs each) + 2 global phase barriers. Staging software-pipelined:
// next K-half's global loads in flight during current dot.
// Decoder: round-7 per-batch WGs (no barriers, bitwise early exit, proven).
// LDS ~135 KB -> 1 WG/CU.
// ---------------------------------------------------------------------------

#define NWG 256
#define THR 512
#define AST 132

// ws word offsets; words [0..3072) = barrier counters (96 lines x 128B)
#define OF_EC0 4096                  // enc l0 final c fp32 [dir*64+b][256]
#define OF_EC1 36864                 // enc l1 final c fp32
#define OF_EH1 69632                 // enc l1 final h fp16 [dir*64+b][256]
#define OF_HB1 86016                 // E1 h dbuf fp16 [buf][dir][b][256]
#define OF_Y0  118784                // y0 fp16 [t][b][512]
#define WS_REQ_BYTES ((size_t)(OF_Y0 + 16777216) * 4)   // ~67.6 MB (<=69.2 proven)

struct SeqParams {
  const float *x, *eWih0, *eWhh0, *eB0, *eWih1, *eWhh1, *eB1;
  const float *dWih0, *dWhh0, *dB0, *dWih1, *dWhh1, *dB1, *fcW, *fcb;
  float* out;
  float* ws;
  unsigned* ctrs;
};

__device__ __forceinline__ float hf2f(unsigned short u) {
  __half_raw r; r.x = u; return __half2float(__half(r));
}
__device__ __forceinline__ unsigned short f2h_u(float f) {
  __half h = __float2half(f);
  return *reinterpret_cast<unsigned short*>(&h);
}
__device__ __forceinline__ float sigm(float v) { return 1.0f / (1.0f + expf(-v)); }

#define FMA4(acc, v, ka) do { \
  acc += (v).x * (ka).x; acc += (v).y * (ka).y; \
  acc += (v).z * (ka).z; acc += (v).w * (ka).w; } while (0)

// ---- barriers (round-4 proven semantics) ----------------------------------
// group barrier: 128 WGs of one dir; 32 lines, 4 WGs/line
__device__ __forceinline__ void gbar_g(unsigned* ctrs, int grp, unsigned gen) {
  __syncthreads();
  if (threadIdx.x == 0) {
    __hip_atomic_fetch_add(&ctrs[(grp * 32 + (blockIdx.x & 31)) * 32], 1u,
                           __ATOMIC_RELEASE, __HIP_MEMORY_SCOPE_AGENT);
  }
  if (threadIdx.x < 32) {
    while (__hip_atomic_load(&ctrs[(grp * 32 + threadIdx.x) * 32], __ATOMIC_RELAXED,
                             __HIP_MEMORY_SCOPE_AGENT) < gen * 4u) {
      __builtin_amdgcn_s_sleep(1);
    }
    (void)__hip_atomic_load(&ctrs[(grp * 32 + threadIdx.x) * 32], __ATOMIC_ACQUIRE,
                            __HIP_MEMORY_SCOPE_AGENT);
  }
  __syncthreads();
}
// global barrier: all 256 WGs; lines 64..95, 8 WGs/line
__device__ __forceinline__ void gbar_all(unsigned* ctrs, unsigned gen) {
  __syncthreads();
  if (threadIdx.x == 0) {
    __hip_atomic_fetch_add(&ctrs[(64 + (blockIdx.x & 31)) * 32], 1u,
                           __ATOMIC_RELEASE, __HIP_MEMORY_SCOPE_AGENT);
  }
  if (threadIdx.x < 32) {
    while (__hip_atomic_load(&ctrs[(64 + threadIdx.x) * 32], __ATOMIC_RELAXED,
                             __HIP_MEMORY_SCOPE_AGENT) < gen * 8u) {
      __builtin_amdgcn_s_sleep(1);
    }
    (void)__hip_atomic_load(&ctrs[(64 + threadIdx.x) * 32], __ATOMIC_ACQUIRE,
                            __HIP_MEMORY_SCOPE_AGENT);
  }
  __syncthreads();
}

// ---- pipelined fp16 staging: 64 rows x 128 halves -> fp32 LDS A[b*AST+k] ---
struct PF { ushort4 v[4]; };
__device__ __forceinline__ void pf_issue(PF& pfb, const unsigned short* src,
                                         int stride, int koff, int t) {
#pragma unroll
  for (int i = 0; i < 4; ++i) {
    int idx = t + i * THR;               // 0..2047 ushort4s
    int b = idx >> 5, kq = (idx & 31) << 2;
    pfb.v[i] = *reinterpret_cast<const ushort4*>(src + (size_t)b * stride + koff + kq);
  }
}
__device__ __forceinline__ void pf_commit(float* A, const PF& pfb, int t) {
#pragma unroll
  for (int i = 0; i < 4; ++i) {
    int idx = t + i * THR;
    int b = idx >> 5, kq = (idx & 31) << 2;
    ushort4 u = pfb.v[i];
    *reinterpret_cast<float4*>(A + b * AST + kq) =
        make_float4(hf2f(u.x), hf2f(u.y), hf2f(u.z), hf2f(u.w));
  }
}
__device__ __forceinline__ void zero_commit(float* A, int t) {
#pragma unroll
  for (int i = 0; i < 4; ++i) {
    int idx = t + i * THR;
    int b = idx >> 5, kq = (idx & 31) << 2;
    *reinterpret_cast<float4*>(A + b * AST + kq) = make_float4(0.f, 0.f, 0.f, 0.f);
  }
}

// stage 8 weight rows x 128 floats from fp32 global.
// wmode 0: gate-major rows for h-cols colbase,colbase+1; wmode 1: grow=colbase+rr.
__device__ __forceinline__ void stage_W_half(float* Wl, const float* src, int stride,
                                             int colbase, int wmode, int koff) {
  const int t = threadIdx.x;
  if (t < 256) {
    int rr = t >> 5, kq = (t & 31) << 2;
    int grow = wmode ? (colbase + rr) : ((rr >> 1) * 256 + colbase + (rr & 1));
    float4 v = *reinterpret_cast<const float4*>(src + (size_t)grow * stride + koff + kq);
    *reinterpret_cast<float4*>(Wl + rr * AST + kq) = v;
  }
}

// r4-proven: acc[i*2+j] += A[bt+16i][k] * W[rt*2+j][k]; kc wave-uniform
__device__ __forceinline__ void dot_half(float4* acc, const float* A, const float* Wl) {
  const int t = threadIdx.x;
  const int kc = t >> 6, tile = t & 63;
  const int bt = tile >> 2, rt = tile & 3;
#pragma unroll
  for (int d = 0; d < 4; ++d) {
    const int k = kc * 16 + d * 4;
    float4 wv[2], hv[4];
#pragma unroll
    for (int j = 0; j < 2; ++j) wv[j] = *reinterpret_cast<const float4*>(Wl + (rt * 2 + j) * AST + k);
#pragma unroll
    for (int i = 0; i < 4; ++i) hv[i] = *reinterpret_cast<const float4*>(A + (bt + 16 * i) * AST + k);
#pragma unroll
    for (int i = 0; i < 4; ++i) {
#pragma unroll
      for (int j = 0; j < 2; ++j) {
        float4& a = acc[i * 2 + j];
        a.x += hv[i].x * wv[j].x;
        a.y += hv[i].y * wv[j].y;
        a.z += hv[i].z * wv[j].z;
        a.w += hv[i].w * wv[j].w;
      }
    }
  }
}

// r4-proven deterministic 8-partial reduction -> gates[r*64+b]
__device__ __forceinline__ void reduce_acc(const float4* acc, float* part, float* outbuf) {
  const int t = threadIdx.x;
  const int kc = t >> 6, tile = t & 63;
#pragma unroll
  for (int e = 0; e < 8; ++e) {
    const float4 a = acc[e];
    part[e * 512 + kc * 64 + tile] = (a.x + a.y) + (a.z + a.w);
  }
  __syncthreads();
  {
    const int r = t >> 6, b = t & 63;
    const int tl = (b & 15) * 4 + (r >> 1);
    const float* pp = part + ((b >> 4) * 2 + (r & 1)) * 512 + tl;
    float v = ((pp[0] + pp[64]) + (pp[128] + pp[192])) +
              ((pp[256] + pp[320]) + (pp[384] + pp[448]));
    outbuf[r * 64 + b] = v;
  }
  __syncthreads();
}

// ---- decoder GEMVs (round-7 proven, fp32) ---------------------------------
__device__ __forceinline__ void gemv1024_k256(const float4* W4, const float* kin,
                                              float* part, int t) {
  const int khalf = t >> 8, rg = t & 255;
  const float4* k4 = (const float4*)kin + khalf * 32;
  float a0 = 0.f, a1 = 0.f, a2 = 0.f, a3 = 0.f;
#pragma unroll 4
  for (int ch = 0; ch < 32; ++ch) {
    float4 ka = k4[ch];
    const float4* Wr = W4 + (4 * rg) * 64 + khalf * 32 + ch;
    float4 v0 = Wr[0];
    float4 v1 = Wr[64];
    float4 v2 = Wr[128];
    float4 v3 = Wr[192];
    FMA4(a0, v0, ka); FMA4(a1, v1, ka);
    FMA4(a2, v2, ka); FMA4(a3, v3, ka);
  }
  part[khalf * 1024 + 4 * rg + 0] = a0;
  part[khalf * 1024 + 4 * rg + 1] = a1;
  part[khalf * 1024 + 4 * rg + 2] = a2;
  part[khalf * 1024 + 4 * rg + 3] = a3;
}

__device__ __forceinline__ void gemv2048_dec(const float4* Wd, const float* kin,
                                             float* part, int t) {
  const int khalf = t >> 8, rg = t & 255;
  float a[8];
#pragma unroll
  for (int i = 0; i < 8; ++i) a[i] = 0.f;
  const float4* k4 = (const float4*)(kin + khalf * 256);
#pragma unroll 2
  for (int ch = 0; ch < 64; ++ch) {
    float4 ka = k4[ch];
#pragma unroll
    for (int ri = 0; ri < 8; ++ri) {
      int r2 = 8 * rg + ri;
      float4 v = Wd[(r2 >> 10) * 131072 + (r2 & 1023) * 128 + khalf * 64 + ch];
      FMA4(a[ri], v, ka);
    }
  }
#pragma unroll
  for (int ri = 0; ri < 8; ++ri) part[khalf * 2048 + 8 * rg + ri] = a[ri];
}

__global__ void __launch_bounds__(THR, 1) seq2seq_kernel(SeqParams p) {
  __shared__ float A0[64 * AST];        // 8448 f
  __shared__ float A1[64 * AST];        // 8448 f
  __shared__ float Wl[6 * 8 * AST];     // 6336 f
  __shared__ float part[4096];          // reduction / decoder partials
  __shared__ float Rl[4096];            // decoder recurrent consts
  __shared__ float kin[1024];           // decoder k-input
  __shared__ float gates[512];
  __shared__ float cst[128];
  __shared__ float xcol[64];
  __shared__ float ph[512];
  __shared__ float red[64];
  __shared__ float ysh[4];
  __shared__ int   exsh;
  __shared__ float cb8[8], cw8[8];

  const int w = blockIdx.x;
  const int t = threadIdx.x;
  float* ws = p.ws;
  unsigned short* y0u  = (unsigned short*)(ws + OF_Y0);
  unsigned short* eh1p = (unsigned short*)(ws + OF_EH1);
  unsigned short* hb1  = (unsigned short*)(ws + OF_HB1);
  unsigned* ctrs = p.ctrs;
  unsigned gen = 0;

  const int dir = w >> 7, wl = w & 127;
  float* Ab[2] = { A0, A1 };

  // ============================ E0 prep ====================================
  stage_W_half(Wl,        p.eWhh0 + (size_t)dir * 262144, 256, 2 * wl, 0, 0);
  stage_W_half(Wl + 1056, p.eWhh0 + (size_t)dir * 262144, 256, 2 * wl, 0, 128);
  if (t < 8) {
    int q = t >> 1, cc = t & 1;
    int grow = q * 256 + 2 * wl + cc;
    cb8[t] = p.eB0[dir * 1024 + grow];
    cw8[t] = p.eWih0[dir * 1024 + grow];
  }
  if (t < 128) cst[t] = 0.f;
  // (round-0 __syncthreads below covers these LDS writes)

  // ============================ E0: 1024 steps =============================
  for (int st = 0; st < 1024; ++st) {
    const int tt = dir ? (1023 - st) : st;
    const int tprev = dir ? (tt + 1) : (tt - 1);
    const int valid = (st > 0);
    const unsigned short* hrow = y0u + (size_t)tprev * 32768 + dir * 256;
    PF pf0, pf1;
    if (valid) pf_issue(pf0, hrow, 512, 0, t);
    float xv = 0.f;
    if (t < 64) xv = p.x[(size_t)t * 1024 + tt];
    if (valid) pf_issue(pf1, hrow, 512, 128, t);
    float4 acc[8];
#pragma unroll
    for (int e = 0; e < 8; ++e) acc[e] = make_float4(0.f, 0.f, 0.f, 0.f);
    if (valid) pf_commit(A0, pf0, t); else zero_commit(A0, t);
    __syncthreads();
    dot_half(acc, A0, Wl);
    if (valid) pf_commit(A1, pf1, t); else zero_commit(A1, t);
    __syncthreads();
    dot_half(acc, A1, Wl + 1056);
    if (t < 64) xcol[t] = xv;
    reduce_acc(acc, part, gates);
    if (t < 128) {
      const int b = t & 63, cc = t >> 6, c = 2 * wl + cc;
      float x2 = xcol[b];
      float gi = gates[(0 + cc) * 64 + b] + cb8[0 + cc] + x2 * cw8[0 + cc];
      float gf = gates[(2 + cc) * 64 + b] + cb8[2 + cc] + x2 * cw8[2 + cc];
      float gg = gates[(4 + cc) * 64 + b] + cb8[4 + cc] + x2 * cw8[4 + cc];
      float go = gates[(6 + cc) * 64 + b] + cb8[6 + cc] + x2 * cw8[6 + cc];
      float cold = cst[cc * 64 + b];
      float cn = sigm(gf) * cold + sigm(gi) * tanhf(gg);
      float hn = sigm(go) * tanhf(cn);
      cst[cc * 64 + b] = cn;
      y0u[(size_t)tt * 32768 + b * 512 + dir * 256 + c] = f2h_u(hn);
      if (st == 1023) ws[OF_EC0 + (size_t)(dir * 64 + b) * 256 + c] = cn;
    }
    gbar_g(ctrs, dir, ++gen);
  }

  gbar_all(ctrs, 1);

  // ============================ E1 prep ====================================
  stage_W_half(Wl,        p.eWhh1 + (size_t)dir * 262144, 256, 2 * wl, 0, 0);
  stage_W_half(Wl + 1056, p.eWhh1 + (size_t)dir * 262144, 256, 2 * wl, 0, 128);
#pragma unroll
  for (int q = 0; q < 4; ++q)
    stage_W_half(Wl + (2 + q) * 1056, p.eWih1 + (size_t)dir * 524288, 512, 2 * wl, 0, q * 128);
  if (t < 8) {
    int q = t >> 1, cc = t & 1;
    cb8[t] = p.eB1[dir * 1024 + q * 256 + 2 * wl + cc];
  }
  if (t < 128) cst[t] = 0.f;

  // ============================ E1: 1024 steps =============================
  for (int st = 0; st < 1024; ++st) {
    const int tt = dir ? (1023 - st) : st;
    const unsigned short* y0row = y0u + (size_t)tt * 32768;
    const unsigned short* hsrc = hb1 + (st & 1) * 32768 + dir * 16384;
    const unsigned short* rs[6] = { y0row, y0row, y0row, y0row, hsrc, hsrc };
    const int rstride[6] = { 512, 512, 512, 512, 256, 256 };
    const int rkoff[6]   = { 0, 128, 256, 384, 0, 128 };
    const int rslot[6]   = { 2, 3, 4, 5, 0, 1 };
    const int rvalid[6]  = { 1, 1, 1, 1, st > 0, st > 0 };
    PF pf[2];
    if (rvalid[0]) pf_issue(pf[0], rs[0], rstride[0], rkoff[0], t);
    float4 acc[8];
#pragma unroll
    for (int e = 0; e < 8; ++e) acc[e] = make_float4(0.f, 0.f, 0.f, 0.f);
#pragma unroll
    for (int r = 0; r < 6; ++r) {
      if (r < 5 && rvalid[r + 1])
        pf_issue(pf[(r + 1) & 1], rs[r + 1], rstride[r + 1], rkoff[r + 1], t);
      if (rvalid[r]) pf_commit(Ab[r & 1], pf[r & 1], t);
      else           zero_commit(Ab[r & 1], t);
      __syncthreads();
      dot_half(acc, Ab[r & 1], Wl + rslot[r] * 1056);
    }
    reduce_acc(acc, part, gates);
    if (t < 128) {
      const int b = t & 63, cc = t >> 6, c = 2 * wl + cc;
      float gi = gates[(0 + cc) * 64 + b] + cb8[0 + cc];
      float gf = gates[(2 + cc) * 64 + b] + cb8[2 + cc];
      float gg = gates[(4 + cc) * 64 + b] + cb8[4 + cc];
      float go = gates[(6 + cc) * 64 + b] + cb8[6 + cc];
      float cold = cst[cc * 64 + b];
      float cn = sigm(gf) * cold + sigm(gi) * tanhf(gg);
      float hn = sigm(go) * tanhf(cn);
      cst[cc * 64 + b] = cn;
      hb1[((st + 1) & 1) * 32768 + dir * 16384 + b * 256 + c] = f2h_u(hn);
      if (st == 1023) {
        eh1p[(size_t)(dir * 64 + b) * 256 + c] = f2h_u(hn);
        ws[OF_EC1 + (size_t)(dir * 64 + b) * 256 + c] = cn;
      }
    }
    gbar_g(ctrs, dir, ++gen);
  }

  gbar_all(ctrs, 2);

  if (w >= 64) return;

  // ====================== decoder (round-7 proven, per-batch) ==============
  {
    const int b = w;
    for (int m = 0; m < 4; ++m) {
      const unsigned short* src =
          (m == 0) ? (y0u + ((size_t)1023 * 64 + b) * 512)
        : (m == 1) ? (y0u + ((size_t)b) * 512 + 256)
                   : (eh1p + (size_t)((m - 2) * 64 + b) * 256);
      const float4* W4 = (m < 2)
          ? (const float4*)(p.dWhh0 + (size_t)(m & 1) * 262144)
          : (const float4*)(p.dWhh1 + (size_t)(m & 1) * 262144);
      const float* bb = (m < 2) ? (p.dB0 + (m & 1) * 1024)
                                : (p.dB1 + (m & 1) * 1024);
      if (t < 256) kin[t] = hf2f(src[t]);
      __syncthreads();
      gemv1024_k256(W4, kin, part, t);
      __syncthreads();
      {
        int r = t;
        Rl[m * 1024 + r] = part[r] + part[1024 + r] + bb[r];
        r = 512 + t;
        Rl[m * 1024 + r] = part[r] + part[1024 + r] + bb[r];
      }
      __syncthreads();
    }

    const int dc = t >> 8, c = t & 255;
    float w0d[4];
#pragma unroll
    for (int g = 0; g < 4; ++g)
      w0d[g] = p.dWih0[dc * 1024 + g * 256 + c];
    const float cold0 = ws[OF_EC0 + (size_t)(dc * 64 + b) * 256 + c];
    const float cold1 = ws[OF_EC1 + (size_t)(dc * 64 + b) * 256 + c];
    const float fw = p.fcW[dc * 256 + c];
    const float fcb = p.fcb[0];
    const float4* Wd = (const float4*)p.dWih1;
    float yp1 = 0.f, yp2 = 0.f;
    if (t < 4) ysh[t] = 0.f;
    if (t == 0) exsh = 0;
    __syncthreads();

    for (int st = 0; st < 1024; ++st) {
      {
        float yv = ysh[0];
        float gi = yv * w0d[0] + Rl[dc * 1024 + c];
        float gf = yv * w0d[1] + Rl[dc * 1024 + 256 + c];
        float gg = yv * w0d[2] + Rl[dc * 1024 + 512 + c];
        float go = yv * w0d[3] + Rl[dc * 1024 + 768 + c];
        float cn = sigm(gf) * cold0 + sigm(gi) * tanhf(gg);
        kin[t] = sigm(go) * tanhf(cn);
      }
      __syncthreads();
      gemv2048_dec(Wd, kin, part, t);
      __syncthreads();
      {
        float gi = part[dc * 1024 + c]       + part[2048 + dc * 1024 + c]       + Rl[(2 + dc) * 1024 + c];
        float gf = part[dc * 1024 + 256 + c] + part[2048 + dc * 1024 + 256 + c] + Rl[(2 + dc) * 1024 + 256 + c];
        float gg = part[dc * 1024 + 512 + c] + part[2048 + dc * 1024 + 512 + c] + Rl[(2 + dc) * 1024 + 512 + c];
        float go = part[dc * 1024 + 768 + c] + part[2048 + dc * 1024 + 768 + c] + Rl[(2 + dc) * 1024 + 768 + c];
        float cn = sigm(gf) * cold1 + sigm(gi) * tanhf(gg);
        float h1 = sigm(go) * tanhf(cn);
        ph[t] = h1 * fw;
      }
      __syncthreads();
      if (t < 64) {
        float s = 0.f;
#pragma unroll
        for (int j = 0; j < 8; ++j) s += ph[t * 8 + j];
        red[t] = s;
      }
      __syncthreads();
      if (t == 0) {
        float y = fcb;
        for (int j = 0; j < 64; ++j) y += red[j];
        unsigned uy = __float_as_uint(y);
        if ((uy & 0x7F800000u) == 0x7F800000u) y = 4096.0f;  // diag: non-finite
        p.out[(size_t)b * 1024 + st] = y;
        int ex = 0;
        if (st >= 1 && __float_as_uint(y) == __float_as_uint(yp1)) ex = 1;
        else if (st >= 2 && __float_as_uint(y) == __float_as_uint(yp2)) ex = 2;
        ysh[1] = yp1;
        yp2 = yp1; yp1 = y;
        ysh[0] = y;
        exsh = ex;
      }
      __syncthreads();
      {
        int ex = exsh;
        if (ex == 1) {
          float y = ysh[0];
          for (int i = st + 1 + t; i < 1024; i += THR)
            p.out[(size_t)b * 1024 + i] = y;
          break;
        }
        if (ex == 2) {
          float y = ysh[0], alt = ysh[1];
          for (int i = st + 1 + t; i < 1024; i += THR)
            p.out[(size_t)b * 1024 + i] = ((i - st) & 1) ? alt : y;
          break;
        }
      }
      __syncthreads();
    }
  }
}

// diagnostic: if ws too small, encode ws_size (MB) into the output signature
__global__ void fill_sig(float* out, int n, float val) {
  int i = blockIdx.x * 256 + threadIdx.x;
  if (i < n) out[i] = val;
}

extern "C" void kernel_launch(void* const* d_in, const int* in_sizes, int n_in,
                              void* d_out, int out_size, void* d_ws, size_t ws_size,
                              hipStream_t stream) {
  (void)in_sizes; (void)n_in;
  if (ws_size < WS_REQ_BYTES) {
    float sig = 2048.0f + (float)(ws_size >> 20);
    fill_sig<<<(out_size + 255) / 256, 256, 0, stream>>>(
        (float*)d_out, out_size, sig);
    return;
  }
  hipMemsetAsync(d_ws, 0, 12288, stream);   // zero barrier counters (96 lines)

  SeqParams p;
  p.x     = (const float*)d_in[0];
  p.eWih0 = (const float*)d_in[1];
  p.eWhh0 = (const float*)d_in[2];
  p.eB0   = (const float*)d_in[3];
  p.eWih1 = (const float*)d_in[4];
  p.eWhh1 = (const float*)d_in[5];
  p.eB1   = (const float*)d_in[6];
  p.dWih0 = (const float*)d_in[7];
  p.dWhh0 = (const float*)d_in[8];
  p.dB0   = (const float*)d_in[9];
  p.dWih1 = (const float*)d_in[10];
  p.dWhh1 = (const float*)d_in[11];
  p.dB1   = (const float*)d_in[12];
  p.fcW   = (const float*)d_in[13];
  p.fcb   = (const float*)d_in[14];
  p.out   = (float*)d_out;
  p.ws    = (float*)d_ws;
  p.ctrs  = (unsigned*)d_ws;

  seq2seq_kernel<<<dim3(NWG), dim3(THR), 0, stream>>>(p);
}